// Round 5
// baseline (110.860 us; speedup 1.0000x reference)
//
#include <hip/hip_runtime.h>
#include <hip/hip_bf16.h>

#define BQ   2
#define NH   12
#define SEQ  2048
#define DIM  64
#define EXQ  64   // end_x (both grids equal -> resample is identity)

#define TENSOR_ELEMS ((size_t)BQ * NH * SEQ * DIM)   // 3,145,728 bf16 each
#define TAB_ROW      128                              // padded dx stride
#define TAB_DYS      63                               // dy in [-31,31]
#define TAB_PER_H    (TAB_DYS * TAB_ROW)              // 8064
#define TAB_ELEMS    (NH * TAB_PER_H)                 // 96768 floats
#define TRIG_ENTRIES (2 * NH * 64 * 8)                // 12288 float4 (c0,s0,c1,s1)
#define ROPE_BLOCKS  6144                             // 2*BQ*NH*SEQ*16 / 256
#define PREP_BLOCKS  ((TAB_ELEMS + TRIG_ENTRIES + 255) / 256)   // 426

typedef __attribute__((ext_vector_type(8))) short short8;
typedef __attribute__((ext_vector_type(4))) float f32x4;

static __device__ __forceinline__ unsigned int pk2bf(float lo, float hi) {
    union { float f; unsigned int u; } a, b; a.f = lo; b.f = hi;
    unsigned int rl = (a.u + 0x7fffu + ((a.u >> 16) & 1u)) >> 16;  // RNE
    unsigned int rh = (b.u + 0x7fffu + ((b.u >> 16) & 1u)) >> 16;
    return (rh << 16) | (rl & 0xffffu);
}

// ---- Phase 0: build decay table + trig LUT ---------------------------------
__global__ __launch_bounds__(256)
void prep_kernel(const float* __restrict__ freqs,   // [2, NH, 16]
                 const float* __restrict__ weight,  // [NH]
                 float* __restrict__ tab,
                 float4* __restrict__ trig)
{
    int e = blockIdx.x * 256 + threadIdx.x;
    if (e < TAB_ELEMS) {
        int h   = e / TAB_PER_H;
        int rem = e % TAB_PER_H;
        int dyi = rem >> 7;
        int dxi = rem & (TAB_ROW - 1);
        float dx = (float)(dxi - 63);
        float dy = (float)(dyi - 31);
        float dist = sqrtf(dx * dx + dy * dy);
        float w  = weight[h];
        float lw = w > 0.f ? w : 0.01f * w;
        tab[e] = exp2f(-1.44269504088896f * lw * dist);
    } else if (e < TAB_ELEMS + TRIG_ENTRIES) {
        int t2   = e - TAB_ELEMS;            // ((axis*NH+h)*64 + t)*8 + fp
        int fp   = t2 & 7;
        int rest = t2 >> 3;
        int tc   = rest & 63;
        int r2   = rest >> 6;                // axis*NH + h
        int h    = r2 % NH;
        int axis = r2 / NH;
        float f0 = freqs[axis * NH * 16 + h * 16 + 2 * fp];
        float f1 = freqs[axis * NH * 16 + h * 16 + 2 * fp + 1];
        float a0 = (float)tc * f0;
        float a1 = (float)tc * f1;
        trig[t2] = make_float4(cosf(a0), sinf(a0), cosf(a1), sinf(a1));
    }
}

// ---- Phase 1: RoPE-rotate q,b -> bf16 ws -----------------------------------
// ws layout: xq bf16[TE] | xb bf16[TE] | tab f32[TAB_ELEMS] | trig float4[...]
template<bool USE_LUT>
__global__ __launch_bounds__(256)
void rope_kernel(const float* __restrict__ qin,
                 const float* __restrict__ bin,
                 const float* __restrict__ freqs,
                 const float4* __restrict__ trig,
                 unsigned int* __restrict__ ws_u32)
{
    int t  = blockIdx.x * 256 + threadIdx.x;
    int p4 = t & 15;                 // quad of elements (2 pairs)
    int n  = (t >> 4) & (SEQ - 1);
    int rest = t >> 15;              // (tensor*BQ+b)*NH + h
    int h    = rest % NH;
    int tb   = rest / NH;
    int tensor = tb >> 1;
    int b      = tb & 1;

    float c0, s0, c1, s1;
    if (USE_LUT) {
        int axis = p4 >> 3;
        int fp   = p4 & 7;
        int tc   = axis ? (n >> 6) : (n & (EXQ - 1));
        float4 cs = trig[((axis * NH + h) * 64 + tc) * 8 + fp];
        c0 = cs.x; s0 = cs.y; c1 = cs.z; s1 = cs.w;
    } else {
        float tx = (float)(n & (EXQ - 1));
        float ty = (float)(n >> 6);
        int pr0 = 2 * p4;
        float f0, f1;
        if (p4 < 8) {
            f0 = freqs[h * 16 + pr0] * tx;
            f1 = freqs[h * 16 + pr0 + 1] * tx;
        } else {
            f0 = freqs[NH * 16 + h * 16 + (pr0 - 16)] * ty;
            f1 = freqs[NH * 16 + h * 16 + (pr0 - 15)] * ty;
        }
        s0 = sinf(f0); c0 = cosf(f0);
        s1 = sinf(f1); c1 = cosf(f1);
    }

    const float* src = tensor ? bin : qin;
    size_t off = ((size_t)(b * NH + h) * SEQ + n) * DIM + 4 * p4;
    float4 v = *reinterpret_cast<const float4*>(src + off);

    float o0 = v.x * c0 - v.y * s0;
    float o1 = v.x * s0 + v.y * c0;
    float o2 = v.z * c1 - v.w * s1;
    float o3 = v.z * s1 + v.w * c1;

    uint2 packed;
    packed.x = pk2bf(o0, o1);
    packed.y = pk2bf(o2, o3);
    size_t uidx = (size_t)tensor * (TENSOR_ELEMS / 2) + (off >> 1);
    *reinterpret_cast<uint2*>(ws_u32 + uidx) = packed;
}

// ---- Phase 2: 128x128 MFMA GEMM + fused decay + LDS-staged coalesced drain -
// Swapped MFMA: acc[i][j] = mfma(bfr[j], afr[i], acc): lane l holds
// row = i*16+(l&15), cols = j*16+(l>>4)*4+{0..3} (wave-tile-local).
// Epilogue stages 64 block-rows at a time in LDS (32 KB, XOR-swizzled), then
// drains with lane-contiguous f32x4 stores (2 rows x 512 B per instruction),
// PLAIN cached stores (the rocclr fill kernel demonstrates 6.9 TB/s this way).
template<bool USE_TAB>
__global__ __launch_bounds__(256, 3)
void gemm_delta_kernel(const unsigned short* __restrict__ ws,
                       const float* __restrict__ tab,
                       const float* __restrict__ weight,
                       float* __restrict__ out)
{
    __shared__ float lds[64 * 128];       // 32 KB half-tile

    const int bh   = blockIdx.z;
    const int h    = bh % NH;
    const int lane = threadIdx.x & 63;
    const int wave = threadIdx.x >> 6;
    const int wr   = wave >> 1, wc = wave & 1;
    const int brow0 = blockIdx.y * 128;   // block tile origin
    const int bcol0 = blockIdx.x * 128;
    const int row0 = brow0 + wr * 64;     // wave tile origin
    const int col0 = bcol0 + wc * 64;

    const unsigned short* xq = ws;
    const unsigned short* xb = ws + TENSOR_ELEMS;

    const int r16 = lane & 15;
    const int kg  = lane >> 4;

    const size_t base = (size_t)bh * SEQ * DIM;

    f32x4 acc[4][4];
#pragma unroll
    for (int i = 0; i < 4; ++i)
#pragma unroll
        for (int j = 0; j < 4; ++j)
            acc[i][j] = (f32x4){0.f, 0.f, 0.f, 0.f};

#pragma unroll
    for (int kk = 0; kk < 2; ++kk) {
        short8 afr[4], bfr[4];
        int k = kk * 32 + kg * 8;
#pragma unroll
        for (int i = 0; i < 4; ++i) {
            int arw = row0 + i * 16 + r16;
            int bcl = col0 + i * 16 + r16;
            afr[i] = *reinterpret_cast<const short8*>(xq + base + (size_t)arw * DIM + k);
            bfr[i] = *reinterpret_cast<const short8*>(xb + base + (size_t)bcl * DIM + k);
        }
#pragma unroll
        for (int i = 0; i < 4; ++i)
#pragma unroll
            for (int j = 0; j < 4; ++j)
                acc[i][j] = __builtin_amdgcn_mfma_f32_16x16x32_bf16(
                    bfr[j], afr[i], acc[i][j], 0, 0, 0);
    }

    // decay params
    const int dyi = (col0 >> 6) - (row0 >> 6) + 31;            // wave-uniform
    const float* tabrow = USE_TAB ? (tab + h * TAB_PER_H + dyi * TAB_ROW + 63)
                                  : nullptr;
    float scale = 0.f;
    if (!USE_TAB) {
        float w  = weight[h];
        float lw = w > 0.f ? w : 0.01f * w;
        scale = -lw * 1.44269504088896f;
    }

#pragma unroll
    for (int half = 0; half < 2; ++half) {
        if (half) __syncthreads();   // drain of previous half must finish
        // ---- apply decay + write to LDS (swizzled) ----
#pragma unroll
        for (int ii = 0; ii < 2; ++ii) {
            const int i  = half * 2 + ii;
            const int qx = i * 16 + r16;              // global row & 63
            const int lrow = wr * 32 + ii * 16 + r16; // LDS row 0..63
#pragma unroll
            for (int j = 0; j < 4; ++j) {
                f32x4 t;
                if (USE_TAB) {
                    const float* rp = tabrow - qx + kg * 4 + j * 16;
                    t[0] = rp[0]; t[1] = rp[1]; t[2] = rp[2]; t[3] = rp[3];
                } else {
                    float qy = (float)((row0 + qx) >> 6);
#pragma unroll
                    for (int r = 0; r < 4; ++r) {
                        int col = col0 + j * 16 + kg * 4 + r;
                        float kx = (float)(col & (EXQ - 1));
                        float ky = (float)(col >> 6);
                        float dx = kx - (float)qx, dy = ky - qy;
                        t[r] = exp2f(scale * sqrtf(dx * dx + dy * dy));
                    }
                }
                int col16 = wc * 16 + j * 4 + kg;          // 16-B slot 0..31
                int slot  = col16 ^ (lrow & 7);            // swizzle
                *reinterpret_cast<f32x4*>(&lds[lrow * 128 + slot * 4]) =
                    acc[i][j] * t;
            }
        }
        __syncthreads();
        // ---- drain: 8 instrs/wave, each 2 rows x 512 B contiguous ----
        const int c32 = lane & 31;                     // linear 16-B slot
#pragma unroll
        for (int tI = 0; tI < 8; ++tI) {
            int lr = wave * 16 + tI * 2 + (lane >> 5); // LDS row 0..63
            int slot = c32 ^ (lr & 7);
            f32x4 v = *reinterpret_cast<const f32x4*>(&lds[lr * 128 + slot * 4]);
            int wr_ = lr >> 5;
            int i   = half * 2 + ((lr >> 4) & 1);
            int grow = brow0 + wr_ * 64 + i * 16 + (lr & 15);
            float* op = out + ((size_t)bh * SEQ + grow) * SEQ + bcol0 + c32 * 4;
            *reinterpret_cast<f32x4*>(op) = v;         // plain cached store
        }
    }
}

extern "C" void kernel_launch(void* const* d_in, const int* in_sizes, int n_in,
                              void* d_out, int out_size, void* d_ws, size_t ws_size,
                              hipStream_t stream) {
    const float* q  = (const float*)d_in[0];
    const float* b  = (const float*)d_in[1];
    const float* fr = (const float*)d_in[2];
    const float* wt = (const float*)d_in[3];
    float* out = (float*)d_out;

    const size_t need_tensors = 2 * TENSOR_ELEMS * sizeof(unsigned short);
    const size_t need_full    = need_tensors + TAB_ELEMS * sizeof(float)
                              + TRIG_ENTRIES * sizeof(float4);
    if (ws_size < need_tensors) return;
    const bool use_tab = ws_size >= need_full;

    unsigned short* ws16 = (unsigned short*)d_ws;
    float*  tab  = (float*)(ws16 + 2 * TENSOR_ELEMS);
    float4* trig = (float4*)(tab + TAB_ELEMS);

    if (use_tab) {
        prep_kernel<<<PREP_BLOCKS, 256, 0, stream>>>(fr, wt, tab, trig);
        rope_kernel<true><<<ROPE_BLOCKS, 256, 0, stream>>>(q, b, fr, trig,
                                                           (unsigned int*)d_ws);
        dim3 grid(SEQ / 128, SEQ / 128, BQ * NH);
        gemm_delta_kernel<true><<<grid, 256, 0, stream>>>(ws16, tab, wt, out);
    } else {
        rope_kernel<false><<<ROPE_BLOCKS, 256, 0, stream>>>(q, b, fr, nullptr,
                                                            (unsigned int*)d_ws);
        dim3 grid(SEQ / 128, SEQ / 128, BQ * NH);
        gemm_delta_kernel<false><<<grid, 256, 0, stream>>>(ws16, tab, wt, out);
    }
}

// Round 6
// 104.481 us; speedup vs baseline: 1.0611x; 1.0611x over previous
//
#include <hip/hip_runtime.h>
#include <hip/hip_bf16.h>

#define BQ   2
#define NH   12
#define SEQ  2048
#define DIM  64
#define EXQ  64   // end_x (both grids equal -> resample is identity)

#define TENSOR_ELEMS ((size_t)BQ * NH * SEQ * DIM)   // 3,145,728 bf16 each
#define ROPE_BLOCKS  6144                             // 2*BQ*NH*SEQ*16 / 256

typedef __attribute__((ext_vector_type(8))) short short8;
typedef __attribute__((ext_vector_type(4))) float f32x4;

static __device__ __forceinline__ unsigned int pk2bf(float lo, float hi) {
    union { float f; unsigned int u; } a, b; a.f = lo; b.f = hi;
    unsigned int rl = (a.u + 0x7fffu + ((a.u >> 16) & 1u)) >> 16;  // RNE
    unsigned int rh = (b.u + 0x7fffu + ((b.u >> 16) & 1u)) >> 16;
    return (rh << 16) | (rl & 0xffffu);
}

// ---- Phase 1: RoPE-rotate q,b -> bf16 ws (inline trig, as in R4) -----------
// ws layout: xq bf16[TENSOR_ELEMS] | xb bf16[TENSOR_ELEMS]
__global__ __launch_bounds__(256)
void rope_kernel(const float* __restrict__ qin,
                 const float* __restrict__ bin,
                 const float* __restrict__ freqs,   // [2, NH, 16]
                 unsigned int* __restrict__ ws_u32)
{
    int t  = blockIdx.x * 256 + threadIdx.x;
    int p4 = t & 15;                 // quad of elements (2 pairs)
    int n  = (t >> 4) & (SEQ - 1);
    int rest = t >> 15;              // (tensor*BQ+b)*NH + h
    int h    = rest % NH;
    int tb   = rest / NH;
    int tensor = tb >> 1;
    int b      = tb & 1;

    float tx = (float)(n & (EXQ - 1));
    float ty = (float)(n >> 6);

    int pr0 = 2 * p4;                // pair indices pr0, pr0+1
    float f0, f1;
    if (p4 < 8) {
        f0 = freqs[h * 16 + pr0] * tx;
        f1 = freqs[h * 16 + pr0 + 1] * tx;
    } else {
        f0 = freqs[NH * 16 + h * 16 + (pr0 - 16)] * ty;
        f1 = freqs[NH * 16 + h * 16 + (pr0 - 15)] * ty;
    }

    const float* src = tensor ? bin : qin;
    size_t off = ((size_t)(b * NH + h) * SEQ + n) * DIM + 4 * p4;
    float4 v = *reinterpret_cast<const float4*>(src + off);

    float s0 = sinf(f0), c0 = cosf(f0);
    float s1 = sinf(f1), c1 = cosf(f1);

    float o0 = v.x * c0 - v.y * s0;
    float o1 = v.x * s0 + v.y * c0;
    float o2 = v.z * c1 - v.w * s1;
    float o3 = v.z * s1 + v.w * c1;

    uint2 packed;
    packed.x = pk2bf(o0, o1);
    packed.y = pk2bf(o2, o3);
    size_t uidx = (size_t)tensor * (TENSOR_ELEMS / 2) + (off >> 1);
    *reinterpret_cast<uint2*>(ws_u32 + uidx) = packed;
}

// ---- Phase 2: 128x128 MFMA GEMM + LDS decay tab + LDS-staged drain ---------
// Swapped MFMA: acc[i][j] = mfma(bfr[j], afr[i], acc): lane l holds
// row = i*16+(l&15), cols = j*16+(l>>4)*4+{0..3} (wave-tile-local).
// Decay factors come from a per-block LDS table with 4 shift-copies so each
// quad's 4 values are one aligned ds_read_b128 (eliminates 64 VMEM loads/thr).
// Epilogue stages 64 rows at a time in LDS, drains with lane-contiguous
// f32x4 NONTEMPORAL stores (no-allocate keeps L2 clean for the xq/xb reads).
__global__ __launch_bounds__(256, 3)
void gemm_delta_kernel(const unsigned short* __restrict__ ws,
                       const float* __restrict__ weight,
                       float* __restrict__ out)
{
    __shared__ float lds[64 * 128];       // 32 KB stage half-tile
    __shared__ float ltab[4 * 3 * 128];   // 6 KB: [shift s][dyrel][x]

    const int bh   = blockIdx.z;
    const int h    = bh % NH;
    const int lane = threadIdx.x & 63;
    const int wave = threadIdx.x >> 6;
    const int wr   = wave >> 1, wc = wave & 1;
    const int brow0 = blockIdx.y * 128;   // block tile origin
    const int bcol0 = blockIdx.x * 128;
    const int row0 = brow0 + wr * 64;     // wave tile origin
    const int col0 = bcol0 + wc * 64;

    const unsigned short* xq = ws;
    const unsigned short* xb = ws + TENSOR_ELEMS;

    const int r16 = lane & 15;
    const int kg  = lane >> 4;

    const size_t base = (size_t)bh * SEQ * DIM;

    // ---- build shifted decay table in LDS ----
    const float w  = weight[h];
    const float lw = w > 0.f ? w : 0.01f * w;
    const float scale = -lw * 1.44269504088896f;
    const int dymid = (bcol0 >> 6) - (brow0 >> 6);
    for (int e = threadIdx.x; e < 4 * 3 * 128; e += 256) {
        int x    = e & 127;
        int rest = e >> 7;           // s*3 + dyrel
        int s    = rest / 3;
        int dyr  = rest - 3 * s;
        float dx = (float)(x + s - 63);
        float dy = (float)(dymid + dyr - 1);
        ltab[e] = exp2f(scale * sqrtf(dx * dx + dy * dy));
    }
    __syncthreads();

    f32x4 acc[4][4];
#pragma unroll
    for (int i = 0; i < 4; ++i)
#pragma unroll
        for (int j = 0; j < 4; ++j)
            acc[i][j] = (f32x4){0.f, 0.f, 0.f, 0.f};

#pragma unroll
    for (int kk = 0; kk < 2; ++kk) {
        short8 afr[4], bfr[4];
        int k = kk * 32 + kg * 8;
#pragma unroll
        for (int i = 0; i < 4; ++i) {
            int arw = row0 + i * 16 + r16;
            int bcl = col0 + i * 16 + r16;
            afr[i] = *reinterpret_cast<const short8*>(xq + base + (size_t)arw * DIM + k);
            bfr[i] = *reinterpret_cast<const short8*>(xb + base + (size_t)bcl * DIM + k);
        }
#pragma unroll
        for (int i = 0; i < 4; ++i)
#pragma unroll
            for (int j = 0; j < 4; ++j)
                acc[i][j] = __builtin_amdgcn_mfma_f32_16x16x32_bf16(
                    bfr[j], afr[i], acc[i][j], 0, 0, 0);
    }

    const int dyrel = (wc - wr) + 1;      // 0..2, wave-uniform

#pragma unroll
    for (int half = 0; half < 2; ++half) {
        if (half) __syncthreads();   // drain of previous half must finish
        // ---- apply decay + write to LDS stage (swizzled) ----
#pragma unroll
        for (int ii = 0; ii < 2; ++ii) {
            const int i  = half * 2 + ii;
            const int qx = i * 16 + r16;              // global row & 63
            const int lrow = wr * 32 + ii * 16 + r16; // LDS row 0..63
#pragma unroll
            for (int j = 0; j < 4; ++j) {
                int dxi_s = 63 - qx + kg * 4 + j * 16;   // window start
                int s     = dxi_s & 3;
                int tbase = dxi_s - s;                   // 16B-aligned
                f32x4 t = *reinterpret_cast<const f32x4*>(
                    &ltab[(s * 3 + dyrel) * 128 + tbase]);
                int col16 = wc * 16 + j * 4 + kg;          // 16-B slot 0..31
                int slot  = col16 ^ (lrow & 7);            // swizzle
                *reinterpret_cast<f32x4*>(&lds[lrow * 128 + slot * 4]) =
                    acc[i][j] * t;
            }
        }
        __syncthreads();
        // ---- drain: 8 instrs/wave, each 2 rows x 512 B contiguous ----
        const int c32 = lane & 31;                     // linear 16-B slot
#pragma unroll
        for (int tI = 0; tI < 8; ++tI) {
            int lr = wave * 16 + tI * 2 + (lane >> 5); // LDS row 0..63
            int slot = c32 ^ (lr & 7);
            f32x4 v = *reinterpret_cast<const f32x4*>(&lds[lr * 128 + slot * 4]);
            int wr_ = lr >> 5;
            int i   = half * 2 + ((lr >> 4) & 1);
            int grow = brow0 + wr_ * 64 + i * 16 + (lr & 15);
            float* op = out + ((size_t)bh * SEQ + grow) * SEQ + bcol0 + c32 * 4;
            __builtin_nontemporal_store(v, reinterpret_cast<f32x4*>(op));
        }
    }
}

extern "C" void kernel_launch(void* const* d_in, const int* in_sizes, int n_in,
                              void* d_out, int out_size, void* d_ws, size_t ws_size,
                              hipStream_t stream) {
    const float* q  = (const float*)d_in[0];
    const float* b  = (const float*)d_in[1];
    const float* fr = (const float*)d_in[2];
    const float* wt = (const float*)d_in[3];
    float* out = (float*)d_out;

    const size_t need_tensors = 2 * TENSOR_ELEMS * sizeof(unsigned short);
    if (ws_size < need_tensors) return;

    unsigned short* ws16 = (unsigned short*)d_ws;

    rope_kernel<<<ROPE_BLOCKS, 256, 0, stream>>>(q, b, fr, (unsigned int*)d_ws);

    dim3 grid(SEQ / 128, SEQ / 128, BQ * NH);
    gemm_delta_kernel<<<grid, 256, 0, stream>>>(ws16, wt, out);
}

// Round 7
// 100.131 us; speedup vs baseline: 1.1072x; 1.0434x over previous
//
#include <hip/hip_runtime.h>
#include <hip/hip_bf16.h>

#define BQ   2
#define NH   12
#define SEQ  2048
#define DIM  64
#define EXQ  64   // end_x (both grids equal -> resample is identity)

#define TENSOR_ELEMS ((size_t)BQ * NH * SEQ * DIM)   // 3,145,728 bf16 each
#define ROPE_BLOCKS  6144                             // 2*BQ*NH*SEQ*16 / 256
#define PERS_BLOCKS  512                              // 2 blocks/CU exact
#define TILES_PER_BLOCK 12                            // 512*12 = 6144 tiles

typedef __attribute__((ext_vector_type(8))) short short8;
typedef __attribute__((ext_vector_type(4))) float f32x4;

static __device__ __forceinline__ unsigned int pk2bf(float lo, float hi) {
    union { float f; unsigned int u; } a, b; a.f = lo; b.f = hi;
    unsigned int rl = (a.u + 0x7fffu + ((a.u >> 16) & 1u)) >> 16;  // RNE
    unsigned int rh = (b.u + 0x7fffu + ((b.u >> 16) & 1u)) >> 16;
    return (rh << 16) | (rl & 0xffffu);
}

// barrier that does NOT drain vmcnt (plain __syncthreads emits vmcnt(0),
// which would stall on our fire-and-forget NT store stream)
static __device__ __forceinline__ void wg_barrier_lds() {
    asm volatile("s_waitcnt lgkmcnt(0)" ::: "memory");
    __builtin_amdgcn_s_barrier();
}

// ---- Phase 1: RoPE-rotate q,b -> bf16 ws (inline trig) ---------------------
// ws layout: xq bf16[TENSOR_ELEMS] | xb bf16[TENSOR_ELEMS]
__global__ __launch_bounds__(256)
void rope_kernel(const float* __restrict__ qin,
                 const float* __restrict__ bin,
                 const float* __restrict__ freqs,   // [2, NH, 16]
                 unsigned int* __restrict__ ws_u32)
{
    int t  = blockIdx.x * 256 + threadIdx.x;
    int p4 = t & 15;                 // quad of elements (2 pairs)
    int n  = (t >> 4) & (SEQ - 1);
    int rest = t >> 15;              // (tensor*BQ+b)*NH + h
    int h    = rest % NH;
    int tb   = rest / NH;
    int tensor = tb >> 1;
    int b      = tb & 1;

    float tx = (float)(n & (EXQ - 1));
    float ty = (float)(n >> 6);

    int pr0 = 2 * p4;                // pair indices pr0, pr0+1
    float f0, f1;
    if (p4 < 8) {
        f0 = freqs[h * 16 + pr0] * tx;
        f1 = freqs[h * 16 + pr0 + 1] * tx;
    } else {
        f0 = freqs[NH * 16 + h * 16 + (pr0 - 16)] * ty;
        f1 = freqs[NH * 16 + h * 16 + (pr0 - 15)] * ty;
    }

    const float* src = tensor ? bin : qin;
    size_t off = ((size_t)(b * NH + h) * SEQ + n) * DIM + 4 * p4;
    float4 v = *reinterpret_cast<const float4*>(src + off);

    float s0 = sinf(f0), c0 = cosf(f0);
    float s1 = sinf(f1), c1 = cosf(f1);

    float o0 = v.x * c0 - v.y * s0;
    float o1 = v.x * s0 + v.y * c0;
    float o2 = v.z * c1 - v.w * s1;
    float o3 = v.z * s1 + v.w * c1;

    uint2 packed;
    packed.x = pk2bf(o0, o1);
    packed.y = pk2bf(o2, o3);
    size_t uidx = (size_t)tensor * (TENSOR_ELEMS / 2) + (off >> 1);
    *reinterpret_cast<uint2*>(ws_u32 + uidx) = packed;
}

// ---- Phase 2: persistent-block 128x128 MFMA GEMM + fused decay -------------
// 512 blocks x 12 tiles. Per tile: MFMA (swapped operands -> lane holds 4
// consecutive cols), in-register decay via 7 shared (j-i) windows computed
// inline, stage full 128x128 tile in 64 KB LDS (XOR swizzle), drain with
// lane-contiguous f32x4 NT stores. Raw lgkm-only barriers; next tile's frag
// loads issue BEFORE this tile's stores so compute overlaps the HBM drain.
__global__ __launch_bounds__(256, 2)
void gemm_delta_kernel(const unsigned short* __restrict__ ws,
                       const float* __restrict__ weight,
                       float* __restrict__ out)
{
    __shared__ float lds[128 * 128];      // 64 KB stage

    const int lane = threadIdx.x & 63;
    const int wave = threadIdx.x >> 6;
    const int wr   = wave >> 1, wc = wave & 1;
    const int r16  = lane & 15;
    const int kg   = lane >> 4;
    const int c32  = lane & 31;

    const unsigned short* xq = ws;
    const unsigned short* xb = ws + TENSOR_ELEMS;

    short8 afr[2][4], bfr[2][4];
    int last_panel = -1;

    // ---- load fragments for tile g ----
    auto load_frags = [&](int g) {
        int bh = g >> 8, rem = g & 255;
        int trow = rem >> 4, tcol = rem & 15;
        const size_t base = (size_t)bh * SEQ * DIM;
        int panel = (bh << 4) | trow;
        if (panel != last_panel) {
            last_panel = panel;
            int row0 = trow * 128 + wr * 64;
#pragma unroll
            for (int kk = 0; kk < 2; ++kk)
#pragma unroll
                for (int i = 0; i < 4; ++i) {
                    int arw = row0 + i * 16 + r16;
                    afr[kk][i] = *reinterpret_cast<const short8*>(
                        xq + base + (size_t)arw * DIM + kk * 32 + kg * 8);
                }
        }
        int col0 = tcol * 128 + wc * 64;
#pragma unroll
        for (int kk = 0; kk < 2; ++kk)
#pragma unroll
            for (int i = 0; i < 4; ++i) {
                int bcl = col0 + i * 16 + r16;
                bfr[kk][i] = *reinterpret_cast<const short8*>(
                    xb + base + (size_t)bcl * DIM + kk * 32 + kg * 8);
            }
    };

    int g0 = blockIdx.x * TILES_PER_BLOCK;
    load_frags(g0);

    for (int t = 0; t < TILES_PER_BLOCK; ++t) {
        const int g    = g0 + t;
        const int bh   = g >> 8, rem = g & 255;
        const int trow = rem >> 4, tcol = rem & 15;
        const int h    = bh % NH;
        const int brow0 = trow * 128, bcol0 = tcol * 128;

        // ---- MFMA ----
        f32x4 acc[4][4];
#pragma unroll
        for (int i = 0; i < 4; ++i)
#pragma unroll
            for (int j = 0; j < 4; ++j)
                acc[i][j] = (f32x4){0.f, 0.f, 0.f, 0.f};
#pragma unroll
        for (int kk = 0; kk < 2; ++kk)
#pragma unroll
            for (int i = 0; i < 4; ++i)
#pragma unroll
                for (int j = 0; j < 4; ++j)
                    acc[i][j] = __builtin_amdgcn_mfma_f32_16x16x32_bf16(
                        bfr[kk][j], afr[kk][i], acc[i][j], 0, 0, 0);

        // ---- in-register decay: 7 shared windows T[d], d = j-i+3 ----
        // window element w: dx = (d-3)*16 + kg*4 - r16 + w, dy wave-uniform
        {
            float w  = weight[h];
            float lw = w > 0.f ? w : 0.01f * w;
            float scale = -lw * 1.44269504088896f;
            float fdy = (float)(2 * (tcol - trow) + (wc - wr));
            float dy2 = fdy * fdy;
            f32x4 T[7];
#pragma unroll
            for (int d = 0; d < 7; ++d) {
                float dx0 = (float)((d - 3) * 16 + kg * 4 - r16);
#pragma unroll
                for (int w_ = 0; w_ < 4; ++w_) {
                    float dx = dx0 + (float)w_;
                    T[d][w_] = exp2f(scale * sqrtf(dx * dx + dy2));
                }
            }
#pragma unroll
            for (int i = 0; i < 4; ++i)
#pragma unroll
                for (int j = 0; j < 4; ++j)
                    acc[i][j] *= T[j - i + 3];
        }

        // ---- prefetch next tile's fragments BEFORE this tile's stores ----
        if (t + 1 < TILES_PER_BLOCK) load_frags(g + 1);
        __builtin_amdgcn_sched_barrier(0);   // keep loads above the stores

        // ---- stage to LDS (swizzled) ----
        wg_barrier_lds();                    // prev drain reads complete
#pragma unroll
        for (int i = 0; i < 4; ++i) {
            int lrow = wr * 64 + i * 16 + r16;       // 0..127
#pragma unroll
            for (int j = 0; j < 4; ++j) {
                int slot = (wc * 16 + j * 4 + kg) ^ (lrow & 7);
                *reinterpret_cast<f32x4*>(&lds[lrow * 128 + slot * 4]) = acc[i][j];
            }
        }
        wg_barrier_lds();                    // stage visible to all waves

        // ---- drain: 16 instrs/wave, each 2 rows x 512 B contiguous ----
        const size_t obase = (size_t)bh * SEQ * SEQ;
#pragma unroll
        for (int tI = 0; tI < 16; ++tI) {
            int lr = wave * 32 + tI * 2 + (lane >> 5);   // 0..127
            int slot = c32 ^ (lr & 7);
            f32x4 v = *reinterpret_cast<const f32x4*>(&lds[lr * 128 + slot * 4]);
            float* op = out + obase + (size_t)(brow0 + lr) * SEQ + bcol0 + c32 * 4;
            __builtin_nontemporal_store(v, reinterpret_cast<f32x4*>(op));
        }
    }
}

extern "C" void kernel_launch(void* const* d_in, const int* in_sizes, int n_in,
                              void* d_out, int out_size, void* d_ws, size_t ws_size,
                              hipStream_t stream) {
    const float* q  = (const float*)d_in[0];
    const float* b  = (const float*)d_in[1];
    const float* fr = (const float*)d_in[2];
    const float* wt = (const float*)d_in[3];
    float* out = (float*)d_out;

    const size_t need = 2 * TENSOR_ELEMS * sizeof(unsigned short);
    if (ws_size < need) return;

    rope_kernel<<<ROPE_BLOCKS, 256, 0, stream>>>(q, b, fr, (unsigned int*)d_ws);

    gemm_delta_kernel<<<PERS_BLOCKS, 256, 0, stream>>>(
        (const unsigned short*)d_ws, wt, out);
}

// Round 8
// 96.821 us; speedup vs baseline: 1.1450x; 1.0342x over previous
//
#include <hip/hip_runtime.h>
#include <hip/hip_bf16.h>

#define BQ   2
#define NH   12
#define SEQ  2048
#define DIM  64
#define EXQ  64   // end_x (both grids equal -> resample is identity)

#define TENSOR_ELEMS ((size_t)BQ * NH * SEQ * DIM)   // 3,145,728 bf16 each
#define ROPE_BLOCKS  6144                             // 2*BQ*NH*SEQ*16 / 256
#define PERS_BLOCKS  512                              // 2 blocks/CU exact
#define TILES_PER_BLOCK 12                            // 512*12 = 6144 tiles

typedef __attribute__((ext_vector_type(8))) short short8;
typedef __attribute__((ext_vector_type(4))) float f32x4;

static __device__ __forceinline__ unsigned int pk2bf(float lo, float hi) {
    union { float f; unsigned int u; } a, b; a.f = lo; b.f = hi;
    unsigned int rl = (a.u + 0x7fffu + ((a.u >> 16) & 1u)) >> 16;  // RNE
    unsigned int rh = (b.u + 0x7fffu + ((b.u >> 16) & 1u)) >> 16;
    return (rh << 16) | (rl & 0xffffu);
}

// barrier that does NOT drain vmcnt (plain __syncthreads emits vmcnt(0),
// which would stall on our fire-and-forget store stream)
static __device__ __forceinline__ void wg_barrier_lds() {
    asm volatile("s_waitcnt lgkmcnt(0)" ::: "memory");
    __builtin_amdgcn_s_barrier();
}

// ---- Phase 1: RoPE-rotate q,b -> bf16 ws (inline trig) ---------------------
// ws layout: xq bf16[TENSOR_ELEMS] | xb bf16[TENSOR_ELEMS]
__global__ __launch_bounds__(256)
void rope_kernel(const float* __restrict__ qin,
                 const float* __restrict__ bin,
                 const float* __restrict__ freqs,   // [2, NH, 16]
                 unsigned int* __restrict__ ws_u32)
{
    int t  = blockIdx.x * 256 + threadIdx.x;
    int p4 = t & 15;                 // quad of elements (2 pairs)
    int n  = (t >> 4) & (SEQ - 1);
    int rest = t >> 15;              // (tensor*BQ+b)*NH + h
    int h    = rest % NH;
    int tb   = rest / NH;
    int tensor = tb >> 1;
    int b      = tb & 1;

    float tx = (float)(n & (EXQ - 1));
    float ty = (float)(n >> 6);

    int pr0 = 2 * p4;                // pair indices pr0, pr0+1
    float f0, f1;
    if (p4 < 8) {
        f0 = freqs[h * 16 + pr0] * tx;
        f1 = freqs[h * 16 + pr0 + 1] * tx;
    } else {
        f0 = freqs[NH * 16 + h * 16 + (pr0 - 16)] * ty;
        f1 = freqs[NH * 16 + h * 16 + (pr0 - 15)] * ty;
    }

    const float* src = tensor ? bin : qin;
    size_t off = ((size_t)(b * NH + h) * SEQ + n) * DIM + 4 * p4;
    float4 v = *reinterpret_cast<const float4*>(src + off);

    float s0 = sinf(f0), c0 = cosf(f0);
    float s1 = sinf(f1), c1 = cosf(f1);

    float o0 = v.x * c0 - v.y * s0;
    float o1 = v.x * s0 + v.y * c0;
    float o2 = v.z * c1 - v.w * s1;
    float o3 = v.z * s1 + v.w * c1;

    uint2 packed;
    packed.x = pk2bf(o0, o1);
    packed.y = pk2bf(o2, o3);
    size_t uidx = (size_t)tensor * (TENSOR_ELEMS / 2) + (off >> 1);
    *reinterpret_cast<uint2*>(ws_u32 + uidx) = packed;
}

// ---- Phase 2: persistent-block 128x128 MFMA GEMM + fused decay -------------
// 512 blocks x 12 tiles. Per tile: MFMA (swapped operands -> lane holds 4
// consecutive cols), in-register decay via 7 shared (j-i) windows computed
// inline, stage full 128x128 tile in 64 KB LDS (XOR swizzle), drain with
// lane-contiguous f32x4 PLAIN stores (A/B vs R7's NT: the rocclr fill proves
// plain stores sustain 6.9 TB/s). Raw lgkm-only barriers; next tile's frag
// loads issue BEFORE this tile's stores so compute overlaps the HBM drain.
__global__ __launch_bounds__(256, 2)
void gemm_delta_kernel(const unsigned short* __restrict__ ws,
                       const float* __restrict__ weight,
                       float* __restrict__ out)
{
    __shared__ float lds[128 * 128];      // 64 KB stage

    const int lane = threadIdx.x & 63;
    const int wave = threadIdx.x >> 6;
    const int wr   = wave >> 1, wc = wave & 1;
    const int r16  = lane & 15;
    const int kg   = lane >> 4;
    const int c32  = lane & 31;

    const unsigned short* xq = ws;
    const unsigned short* xb = ws + TENSOR_ELEMS;

    short8 afr[2][4], bfr[2][4];
    int last_panel = -1;

    // ---- load fragments for tile g ----
    auto load_frags = [&](int g) {
        int bh = g >> 8, rem = g & 255;
        int trow = rem >> 4, tcol = rem & 15;
        const size_t base = (size_t)bh * SEQ * DIM;
        int panel = (bh << 4) | trow;
        if (panel != last_panel) {
            last_panel = panel;
            int row0 = trow * 128 + wr * 64;
#pragma unroll
            for (int kk = 0; kk < 2; ++kk)
#pragma unroll
                for (int i = 0; i < 4; ++i) {
                    int arw = row0 + i * 16 + r16;
                    afr[kk][i] = *reinterpret_cast<const short8*>(
                        xq + base + (size_t)arw * DIM + kk * 32 + kg * 8);
                }
        }
        int col0 = tcol * 128 + wc * 64;
#pragma unroll
        for (int kk = 0; kk < 2; ++kk)
#pragma unroll
            for (int i = 0; i < 4; ++i) {
                int bcl = col0 + i * 16 + r16;
                bfr[kk][i] = *reinterpret_cast<const short8*>(
                    xb + base + (size_t)bcl * DIM + kk * 32 + kg * 8);
            }
    };

    int g0 = blockIdx.x * TILES_PER_BLOCK;
    load_frags(g0);

    for (int t = 0; t < TILES_PER_BLOCK; ++t) {
        const int g    = g0 + t;
        const int bh   = g >> 8, rem = g & 255;
        const int trow = rem >> 4, tcol = rem & 15;
        const int h    = bh % NH;
        const int brow0 = trow * 128, bcol0 = tcol * 128;

        // ---- MFMA ----
        f32x4 acc[4][4];
#pragma unroll
        for (int i = 0; i < 4; ++i)
#pragma unroll
            for (int j = 0; j < 4; ++j)
                acc[i][j] = (f32x4){0.f, 0.f, 0.f, 0.f};
#pragma unroll
        for (int kk = 0; kk < 2; ++kk)
#pragma unroll
            for (int i = 0; i < 4; ++i)
#pragma unroll
                for (int j = 0; j < 4; ++j)
                    acc[i][j] = __builtin_amdgcn_mfma_f32_16x16x32_bf16(
                        bfr[kk][j], afr[kk][i], acc[i][j], 0, 0, 0);

        // ---- in-register decay: 7 shared windows T[d], d = j-i+3 ----
        // window element w: dx = (d-3)*16 + kg*4 - r16 + w, dy wave-uniform
        {
            float w  = weight[h];
            float lw = w > 0.f ? w : 0.01f * w;
            float scale = -lw * 1.44269504088896f;
            float fdy = (float)(2 * (tcol - trow) + (wc - wr));
            float dy2 = fdy * fdy;
            f32x4 T[7];
#pragma unroll
            for (int d = 0; d < 7; ++d) {
                float dx0 = (float)((d - 3) * 16 + kg * 4 - r16);
#pragma unroll
                for (int w_ = 0; w_ < 4; ++w_) {
                    float dx = dx0 + (float)w_;
                    T[d][w_] = exp2f(scale * sqrtf(dx * dx + dy2));
                }
            }
#pragma unroll
            for (int i = 0; i < 4; ++i)
#pragma unroll
                for (int j = 0; j < 4; ++j)
                    acc[i][j] *= T[j - i + 3];
        }

        // ---- prefetch next tile's fragments BEFORE this tile's stores ----
        if (t + 1 < TILES_PER_BLOCK) load_frags(g + 1);
        __builtin_amdgcn_sched_barrier(0);   // keep loads above the stores

        // ---- stage to LDS (swizzled) ----
        wg_barrier_lds();                    // prev drain reads complete
#pragma unroll
        for (int i = 0; i < 4; ++i) {
            int lrow = wr * 64 + i * 16 + r16;       // 0..127
#pragma unroll
            for (int j = 0; j < 4; ++j) {
                int slot = (wc * 16 + j * 4 + kg) ^ (lrow & 7);
                *reinterpret_cast<f32x4*>(&lds[lrow * 128 + slot * 4]) = acc[i][j];
            }
        }
        wg_barrier_lds();                    // stage visible to all waves

        // ---- drain: 16 instrs/wave, each 2 rows x 512 B contiguous ----
        const size_t obase = (size_t)bh * SEQ * SEQ;
#pragma unroll
        for (int tI = 0; tI < 16; ++tI) {
            int lr = wave * 32 + tI * 2 + (lane >> 5);   // 0..127
            int slot = c32 ^ (lr & 7);
            f32x4 v = *reinterpret_cast<const f32x4*>(&lds[lr * 128 + slot * 4]);
            float* op = out + obase + (size_t)(brow0 + lr) * SEQ + bcol0 + c32 * 4;
            *reinterpret_cast<f32x4*>(op) = v;           // PLAIN store (A/B vs NT)
        }
    }
}

extern "C" void kernel_launch(void* const* d_in, const int* in_sizes, int n_in,
                              void* d_out, int out_size, void* d_ws, size_t ws_size,
                              hipStream_t stream) {
    const float* q  = (const float*)d_in[0];
    const float* b  = (const float*)d_in[1];
    const float* fr = (const float*)d_in[2];
    const float* wt = (const float*)d_in[3];
    float* out = (float*)d_out;

    const size_t need = 2 * TENSOR_ELEMS * sizeof(unsigned short);
    if (ws_size < need) return;

    rope_kernel<<<ROPE_BLOCKS, 256, 0, stream>>>(q, b, fr, (unsigned int*)d_ws);

    gemm_delta_kernel<<<PERS_BLOCKS, 256, 0, stream>>>(
        (const unsigned short*)d_ws, wt, out);
}

// Round 9
// 93.561 us; speedup vs baseline: 1.1849x; 1.0348x over previous
//
#include <hip/hip_runtime.h>
#include <hip/hip_bf16.h>

#define BQ   2
#define NH   12
#define SEQ  2048
#define DIM  64
#define EXQ  64   // end_x (both grids equal -> resample is identity)

#define TENSOR_ELEMS ((size_t)BQ * NH * SEQ * DIM)   // 3,145,728 bf16 each
#define ROPE_BLOCKS  6144                             // 2*BQ*NH*SEQ*16 / 256
#define PERS_BLOCKS  512                              // 2 blocks/CU exact
#define TILES_PER_BLOCK 12                            // 512*12 = 6144 tiles

typedef __attribute__((ext_vector_type(8))) short short8;
typedef __attribute__((ext_vector_type(4))) float f32x4;

static __device__ __forceinline__ unsigned int pk2bf(float lo, float hi) {
    union { float f; unsigned int u; } a, b; a.f = lo; b.f = hi;
    unsigned int rl = (a.u + 0x7fffu + ((a.u >> 16) & 1u)) >> 16;  // RNE
    unsigned int rh = (b.u + 0x7fffu + ((b.u >> 16) & 1u)) >> 16;
    return (rh << 16) | (rl & 0xffffu);
}

// barrier that does NOT drain vmcnt (plain __syncthreads emits vmcnt(0),
// which would stall on our fire-and-forget store stream)
static __device__ __forceinline__ void wg_barrier_lds() {
    asm volatile("s_waitcnt lgkmcnt(0)" ::: "memory");
    __builtin_amdgcn_s_barrier();
}

// ---- Phase 1: RoPE-rotate q,b -> bf16 ws (fast HW trig) --------------------
// ws layout: xq bf16[TENSOR_ELEMS] | xb bf16[TENSOR_ELEMS]
__global__ __launch_bounds__(256)
void rope_kernel(const float* __restrict__ qin,
                 const float* __restrict__ bin,
                 const float* __restrict__ freqs,   // [2, NH, 16]
                 unsigned int* __restrict__ ws_u32)
{
    int t  = blockIdx.x * 256 + threadIdx.x;
    int p4 = t & 15;                 // quad of elements (2 pairs)
    int n  = (t >> 4) & (SEQ - 1);
    int rest = t >> 15;              // (tensor*BQ+b)*NH + h
    int h    = rest % NH;
    int tb   = rest / NH;
    int tensor = tb >> 1;
    int b      = tb & 1;

    float tx = (float)(n & (EXQ - 1));
    float ty = (float)(n >> 6);

    int pr0 = 2 * p4;                // pair indices pr0, pr0+1
    float f0, f1;
    if (p4 < 8) {
        f0 = freqs[h * 16 + pr0] * tx;
        f1 = freqs[h * 16 + pr0 + 1] * tx;
    } else {
        f0 = freqs[NH * 16 + h * 16 + (pr0 - 16)] * ty;
        f1 = freqs[NH * 16 + h * 16 + (pr0 - 15)] * ty;
    }

    const float* src = tensor ? bin : qin;
    size_t off = ((size_t)(b * NH + h) * SEQ + n) * DIM + 4 * p4;
    float4 v = *reinterpret_cast<const float4*>(src + off);

    float s0 = __sinf(f0), c0 = __cosf(f0);   // v_sin/v_cos fast path
    float s1 = __sinf(f1), c1 = __cosf(f1);

    float o0 = v.x * c0 - v.y * s0;
    float o1 = v.x * s0 + v.y * c0;
    float o2 = v.z * c1 - v.w * s1;
    float o3 = v.z * s1 + v.w * c1;

    uint2 packed;
    packed.x = pk2bf(o0, o1);
    packed.y = pk2bf(o2, o3);
    size_t uidx = (size_t)tensor * (TENSOR_ELEMS / 2) + (off >> 1);
    *reinterpret_cast<uint2*>(ws_u32 + uidx) = packed;
}

// ---- Phase 2: persistent-block 128x128 MFMA GEMM + fused decay -------------
// 512 blocks x 12 tiles. Per tile: MFMA (swapped operands -> lane holds 4
// consecutive cols), in-register decay via 7 shared (j-i) windows computed
// with RAW v_sqrt_f32 / v_exp_f32 (single-instr; libm sqrtf/exp2f are long
// correctly-rounded sequences that were not hiding under the store drain),
// stage full 128x128 tile in 64 KB LDS (XOR swizzle), drain with
// lane-contiguous f32x4 PLAIN stores. Raw lgkm-only barriers; next tile's
// frag loads issue BEFORE this tile's stores so compute overlaps HBM drain.
__global__ __launch_bounds__(256, 2)
void gemm_delta_kernel(const unsigned short* __restrict__ ws,
                       const float* __restrict__ weight,
                       float* __restrict__ out)
{
    __shared__ float lds[128 * 128];      // 64 KB stage

    const int lane = threadIdx.x & 63;
    const int wave = threadIdx.x >> 6;
    const int wr   = wave >> 1, wc = wave & 1;
    const int r16  = lane & 15;
    const int kg   = lane >> 4;
    const int c32  = lane & 31;

    const unsigned short* xq = ws;
    const unsigned short* xb = ws + TENSOR_ELEMS;

    short8 afr[2][4], bfr[2][4];
    int last_panel = -1;

    // ---- load fragments for tile g ----
    auto load_frags = [&](int g) {
        int bh = g >> 8, rem = g & 255;
        int trow = rem >> 4, tcol = rem & 15;
        const size_t base = (size_t)bh * SEQ * DIM;
        int panel = (bh << 4) | trow;
        if (panel != last_panel) {
            last_panel = panel;
            int row0 = trow * 128 + wr * 64;
#pragma unroll
            for (int kk = 0; kk < 2; ++kk)
#pragma unroll
                for (int i = 0; i < 4; ++i) {
                    int arw = row0 + i * 16 + r16;
                    afr[kk][i] = *reinterpret_cast<const short8*>(
                        xq + base + (size_t)arw * DIM + kk * 32 + kg * 8);
                }
        }
        int col0 = tcol * 128 + wc * 64;
#pragma unroll
        for (int kk = 0; kk < 2; ++kk)
#pragma unroll
            for (int i = 0; i < 4; ++i) {
                int bcl = col0 + i * 16 + r16;
                bfr[kk][i] = *reinterpret_cast<const short8*>(
                    xb + base + (size_t)bcl * DIM + kk * 32 + kg * 8);
            }
    };

    int g0 = blockIdx.x * TILES_PER_BLOCK;
    load_frags(g0);

    for (int t = 0; t < TILES_PER_BLOCK; ++t) {
        const int g    = g0 + t;
        const int bh   = g >> 8, rem = g & 255;
        const int trow = rem >> 4, tcol = rem & 15;
        const int h    = bh % NH;
        const int brow0 = trow * 128, bcol0 = tcol * 128;

        // ---- MFMA ----
        f32x4 acc[4][4];
#pragma unroll
        for (int i = 0; i < 4; ++i)
#pragma unroll
            for (int j = 0; j < 4; ++j)
                acc[i][j] = (f32x4){0.f, 0.f, 0.f, 0.f};
#pragma unroll
        for (int kk = 0; kk < 2; ++kk)
#pragma unroll
            for (int i = 0; i < 4; ++i)
#pragma unroll
                for (int j = 0; j < 4; ++j)
                    acc[i][j] = __builtin_amdgcn_mfma_f32_16x16x32_bf16(
                        bfr[kk][j], afr[kk][i], acc[i][j], 0, 0, 0);

        // ---- in-register decay: 7 shared windows T[d], d = j-i+3 ----
        // window element w: dx = (d-3)*16 + kg*4 - r16 + w, dy wave-uniform
        {
            float w  = weight[h];
            float lw = w > 0.f ? w : 0.01f * w;
            float scale = -lw * 1.44269504088896f;
            float fdy = (float)(2 * (tcol - trow) + (wc - wr));
            float dy2 = fdy * fdy;
            f32x4 T[7];
#pragma unroll
            for (int d = 0; d < 7; ++d) {
                float dx0 = (float)((d - 3) * 16 + kg * 4 - r16);
#pragma unroll
                for (int w_ = 0; w_ < 4; ++w_) {
                    float dx = dx0 + (float)w_;
                    float dist = __builtin_amdgcn_sqrtf(dx * dx + dy2);
                    T[d][w_] = __builtin_amdgcn_exp2f(scale * dist);
                }
            }
#pragma unroll
            for (int i = 0; i < 4; ++i)
#pragma unroll
                for (int j = 0; j < 4; ++j)
                    acc[i][j] *= T[j - i + 3];
        }

        // ---- prefetch next tile's fragments BEFORE this tile's stores ----
        if (t + 1 < TILES_PER_BLOCK) load_frags(g + 1);
        __builtin_amdgcn_sched_barrier(0);   // keep loads above the stores

        // ---- stage to LDS (swizzled) ----
        wg_barrier_lds();                    // prev drain reads complete
#pragma unroll
        for (int i = 0; i < 4; ++i) {
            int lrow = wr * 64 + i * 16 + r16;       // 0..127
#pragma unroll
            for (int j = 0; j < 4; ++j) {
                int slot = (wc * 16 + j * 4 + kg) ^ (lrow & 7);
                *reinterpret_cast<f32x4*>(&lds[lrow * 128 + slot * 4]) = acc[i][j];
            }
        }
        wg_barrier_lds();                    // stage visible to all waves

        // ---- drain: 16 instrs/wave, each 2 rows x 512 B contiguous ----
        const size_t obase = (size_t)bh * SEQ * SEQ;
#pragma unroll
        for (int tI = 0; tI < 16; ++tI) {
            int lr = wave * 32 + tI * 2 + (lane >> 5);   // 0..127
            int slot = c32 ^ (lr & 7);
            f32x4 v = *reinterpret_cast<const f32x4*>(&lds[lr * 128 + slot * 4]);
            float* op = out + obase + (size_t)(brow0 + lr) * SEQ + bcol0 + c32 * 4;
            *reinterpret_cast<f32x4*>(op) = v;           // plain store
        }
    }
}

extern "C" void kernel_launch(void* const* d_in, const int* in_sizes, int n_in,
                              void* d_out, int out_size, void* d_ws, size_t ws_size,
                              hipStream_t stream) {
    const float* q  = (const float*)d_in[0];
    const float* b  = (const float*)d_in[1];
    const float* fr = (const float*)d_in[2];
    const float* wt = (const float*)d_in[3];
    float* out = (float*)d_out;

    const size_t need = 2 * TENSOR_ELEMS * sizeof(unsigned short);
    if (ws_size < need) return;

    rope_kernel<<<ROPE_BLOCKS, 256, 0, stream>>>(q, b, fr, (unsigned int*)d_ws);

    gemm_delta_kernel<<<PERS_BLOCKS, 256, 0, stream>>>(
        (const unsigned short*)d_ws, wt, out);
}